// Round 1
// baseline (742.563 us; speedup 1.0000x reference)
//
#include <hip/hip_runtime.h>
#include <hip/hip_bf16.h>
#include <math.h>

// Problem constants
#define NROWS 131072      // 32*64*64
#define DDIM  64
#define KCODE 1024
#define TAU   0.05f

// d_out layout (float elements, return order)
#define OFF_Q    0L
#define OFF_LOSS 8388608L
#define OFF_PERP 8388609L
#define OFF_ENC  8388610L
#define OFF_IDX  (OFF_ENC + 134217728L)   // 142606338
#define OFF_DIST (OFF_IDX + 131072L)      // 142737410

// ws layout (float elements)
#define WS_ENORM 0L          // 1024 f
#define WS_ET    1024L       // 65536 f  (eT[k][d])
#define WS_IDX   66560L      // 131072 int
#define WS_CNT   197632L     // 1024 int (histogram)
#define WS_CTR   198656L     // 1 int
#define WS_LIST  198660L     // 131072 int
#define WS_PART  329732L     // 8192 f

// ---------------- k1: e-norms, transpose, zero histogram/counter ----------------
__global__ __launch_bounds__(256) void k1_prep(const float* __restrict__ e,
                                               float* __restrict__ enorm,
                                               float* __restrict__ eT,
                                               int* __restrict__ cnt,
                                               int* __restrict__ counter) {
    int k = blockIdx.x * 256 + threadIdx.x;   // grid=4 -> k in [0,1024)
    float s = 0.f;
    #pragma unroll 8
    for (int d = 0; d < DDIM; ++d) {
        float v = e[(size_t)d * KCODE + k];
        s += v * v;
        eT[(size_t)k * DDIM + d] = v;
    }
    enorm[k] = s;
    cnt[k] = 0;
    if (k == 0) counter[0] = 0;
}

// ---------------- k2: distances GEMM + enc zeros + per-row argmin ----------------
// block = 256 threads, 16 rows/block. wave w owns rows w*4..w*4+3, lane owns
// k = 256*g + lane*4 + c (g=0..3, c=0..3) -> acc[4][16].
__global__ __launch_bounds__(256) void k2_dist(const float* __restrict__ x,
                                               const float* __restrict__ e,
                                               const float* __restrict__ enorm,
                                               float* __restrict__ dist,
                                               float* __restrict__ enc,
                                               int* __restrict__ idxarr,
                                               int* __restrict__ counter,
                                               int* __restrict__ list) {
    __shared__ float xs[16][65];
    __shared__ float xn[16];
    __shared__ __align__(16) float en[KCODE];

    const int tid  = threadIdx.x;
    const int lane = tid & 63;
    const int w    = tid >> 6;
    const long rowbase = (long)blockIdx.x * 16;

    // load x tile (16 rows x 64 = 1024 contiguous floats)
    {
        const float4* src = (const float4*)(x + rowbase * DDIM);
        float4 v = src[tid];
        int fi = tid * 4;
        int r = fi >> 6, c = fi & 63;
        xs[r][c]     = v.x;
        xs[r][c + 1] = v.y;
        xs[r][c + 2] = v.z;
        xs[r][c + 3] = v.w;
        ((float4*)en)[tid] = ((const float4*)enorm)[tid];
    }
    __syncthreads();
    if (tid < 16) {
        float s = 0.f;
        #pragma unroll 8
        for (int d = 0; d < DDIM; ++d) s += xs[tid][d] * xs[tid][d];
        xn[tid] = s;
    }
    __syncthreads();

    const int r0 = w * 4;
    float acc[4][16];
    #pragma unroll
    for (int i = 0; i < 4; ++i)
        #pragma unroll
        for (int j = 0; j < 16; ++j) acc[i][j] = 0.f;

    #pragma unroll 4
    for (int d = 0; d < DDIM; ++d) {
        float a0 = xs[r0][d], a1 = xs[r0 + 1][d], a2 = xs[r0 + 2][d], a3 = xs[r0 + 3][d];
        const float4* ep = (const float4*)(e + (size_t)d * KCODE + (lane << 2));
        float4 b0 = ep[0];    // k = lane*4 + 0
        float4 b1 = ep[64];   // +256
        float4 b2 = ep[128];  // +512
        float4 b3 = ep[192];  // +768
        float b[16] = {b0.x, b0.y, b0.z, b0.w, b1.x, b1.y, b1.z, b1.w,
                       b2.x, b2.y, b2.z, b2.w, b3.x, b3.y, b3.z, b3.w};
        float a[4] = {a0, a1, a2, a3};
        #pragma unroll
        for (int i = 0; i < 4; ++i)
            #pragma unroll
            for (int j = 0; j < 16; ++j)
                acc[i][j] = fmaf(a[i], b[j], acc[i][j]);
    }

    // epilogue: dist = ||x||^2 - 2*acc + ||e||^2 ; stream zeros to encodings;
    // per-row (min1, idx1, min2) with first-index tie-break.
    const float2 z2 = make_float2(0.f, 0.f);
    #pragma unroll
    for (int i = 0; i < 4; ++i) {
        const long row = rowbase + r0 + i;
        const float xnv = xn[r0 + i];
        float* drow = dist + row * (long)KCODE;
        float* erow = enc  + row * (long)KCODE;
        float m1 = 3.4e38f, m2 = 3.4e38f;
        int   i1 = 1 << 30;
        #pragma unroll
        for (int g = 0; g < 4; ++g) {
            float dv[4];
            #pragma unroll
            for (int c = 0; c < 4; ++c) {
                int kk = (g << 8) + (lane << 2) + c;
                float v = fmaf(-2.f, acc[i][g * 4 + c], xnv) + en[kk];
                dv[c] = v;
                if (v < m1 || (v == m1 && kk < i1)) { m2 = m1; m1 = v; i1 = kk; }
                else if (v < m2) m2 = v;
            }
            float2* dp = (float2*)(drow + (g << 8) + (lane << 2));
            dp[0] = make_float2(dv[0], dv[1]);
            dp[1] = make_float2(dv[2], dv[3]);
            float2* ez = (float2*)(erow + (g << 8) + (lane << 2));
            ez[0] = z2;
            ez[1] = z2;
        }
        // wave-wide (64-lane) argmin reduce keeping 2nd-best value
        #pragma unroll
        for (int m = 1; m < 64; m <<= 1) {
            float pm1 = __shfl_xor(m1, m);
            int   pi1 = __shfl_xor(i1, m);
            float pm2 = __shfl_xor(m2, m);
            if (pm1 < m1 || (pm1 == m1 && pi1 < i1)) {
                m2 = fminf(m1, pm2); m1 = pm1; i1 = pi1;
            } else {
                m2 = fminf(m2, pm1);
            }
        }
        if (lane == 0) {
            idxarr[row] = i1;
            if (m2 - m1 < TAU) {            // near-tie: refine in f64 later
                int p = atomicAdd(counter, 1);
                list[p] = (int)row;
            }
        }
    }
}

// ---------------- k3: f64 refinement of near-tie rows ----------------
__global__ __launch_bounds__(256) void k3_refine(const float* __restrict__ x,
                                                 const float* __restrict__ e,
                                                 const int* __restrict__ list,
                                                 const int* __restrict__ counter,
                                                 int* __restrict__ idxarr) {
    const int cntv = counter[0];
    __shared__ double bv[256];
    __shared__ int    bi[256];
    __shared__ float  xsh[DDIM];
    const int tid = threadIdx.x;
    for (int li = blockIdx.x; li < cntv; li += gridDim.x) {
        const int n = list[li];
        if (tid < DDIM) xsh[tid] = x[(size_t)n * DDIM + tid];
        __syncthreads();
        const int k0 = tid * 4;
        double dd[4] = {0.0, 0.0, 0.0, 0.0};
        for (int d = 0; d < DDIM; ++d) {
            double xd = (double)xsh[d];
            float4 ev = *(const float4*)(e + (size_t)d * KCODE + k0);
            double t0 = xd - (double)ev.x; dd[0] += t0 * t0;
            double t1 = xd - (double)ev.y; dd[1] += t1 * t1;
            double t2 = xd - (double)ev.z; dd[2] += t2 * t2;
            double t3 = xd - (double)ev.w; dd[3] += t3 * t3;
        }
        double best = dd[0]; int bidx = k0;
        #pragma unroll
        for (int c = 1; c < 4; ++c)
            if (dd[c] < best) { best = dd[c]; bidx = k0 + c; }
        bv[tid] = best; bi[tid] = bidx;
        __syncthreads();
        for (int s = 128; s > 0; s >>= 1) {
            if (tid < s) {
                if (bv[tid + s] < bv[tid] ||
                    (bv[tid + s] == bv[tid] && bi[tid + s] < bi[tid])) {
                    bv[tid] = bv[tid + s]; bi[tid] = bi[tid + s];
                }
            }
            __syncthreads();
        }
        if (tid == 0) idxarr[n] = bi[0];
        __syncthreads();
    }
}

// ---------------- k5: gather quantized, scatter one-hot, indices, SSE, histogram ----------------
__global__ __launch_bounds__(256) void k5_final(const float* __restrict__ x,
                                                const float* __restrict__ eT,
                                                const int* __restrict__ idxarr,
                                                float* __restrict__ outq,
                                                float* __restrict__ enc,
                                                float* __restrict__ outidx,
                                                int* __restrict__ cnt,
                                                float* __restrict__ partials) {
    const int tid  = threadIdx.x;
    const int lane = tid & 63;
    const int w    = tid >> 6;
    const long blk = blockIdx.x;
    float sse = 0.f;
    #pragma unroll
    for (int i = 0; i < 4; ++i) {
        const long row = blk * 16 + w * 4 + i;
        const int idx = idxarr[row];
        const float q  = eT[(size_t)idx * DDIM + lane];
        const float xv = x[row * DDIM + lane];
        const float df = q - xv;
        sse = fmaf(df, df, sse);
        outq[row * DDIM + lane] = q;
        if (lane == 0) {
            outidx[row] = (float)idx;
            enc[row * (long)KCODE + idx] = 1.0f;
            atomicAdd(cnt + idx, 1);
        }
    }
    #pragma unroll
    for (int m = 1; m < 64; m <<= 1) sse += __shfl_xor(sse, m);
    __shared__ float ps[4];
    if (lane == 0) ps[w] = sse;
    __syncthreads();
    if (tid == 0) partials[blk] = ps[0] + ps[1] + ps[2] + ps[3];
}

// ---------------- k6: loss + perplexity ----------------
__global__ __launch_bounds__(256) void k6_scalar(const float* __restrict__ partials,
                                                 const int* __restrict__ cnt,
                                                 float* __restrict__ outloss,
                                                 float* __restrict__ outperp) {
    __shared__ double sd[256];
    const int tid = threadIdx.x;
    double s = 0.0;
    for (int i = tid; i < 8192; i += 256) s += (double)partials[i];
    sd[tid] = s;
    __syncthreads();
    for (int st = 128; st > 0; st >>= 1) {
        if (tid < st) sd[tid] += sd[tid + st];
        __syncthreads();
    }
    const double total = sd[0];
    __syncthreads();
    double h = 0.0;
    for (int k = tid; k < KCODE; k += 256) {
        double p = (double)cnt[k] / (double)NROWS;
        h -= p * log(p + 1e-10);
    }
    sd[tid] = h;
    __syncthreads();
    for (int st = 128; st > 0; st >>= 1) {
        if (tid < st) sd[tid] += sd[tid + st];
        __syncthreads();
    }
    if (tid == 0) {
        *outloss = (float)(total * 1.25 / (double)(NROWS * (long)DDIM));
        *outperp = (float)exp(sd[0]);
    }
}

extern "C" void kernel_launch(void* const* d_in, const int* in_sizes, int n_in,
                              void* d_out, int out_size, void* d_ws, size_t ws_size,
                              hipStream_t stream) {
    const float* x = (const float*)d_in[0];       // [131072, 64]
    const float* e = (const float*)d_in[1];       // [64, 1024]
    float* out = (float*)d_out;

    float* ws_f = (float*)d_ws;
    float* enorm   = ws_f + WS_ENORM;
    float* eT      = ws_f + WS_ET;
    int*   idxarr  = (int*)(ws_f + WS_IDX);
    int*   cnt     = (int*)(ws_f + WS_CNT);
    int*   counter = (int*)(ws_f + WS_CTR);
    int*   list    = (int*)(ws_f + WS_LIST);
    float* partials= ws_f + WS_PART;

    float* outq    = out + OFF_Q;
    float* outloss = out + OFF_LOSS;
    float* outperp = out + OFF_PERP;
    float* enc     = out + OFF_ENC;
    float* outidx  = out + OFF_IDX;
    float* dist    = out + OFF_DIST;

    hipLaunchKernelGGL(k1_prep,   dim3(4),    dim3(256), 0, stream, e, enorm, eT, cnt, counter);
    hipLaunchKernelGGL(k2_dist,   dim3(8192), dim3(256), 0, stream, x, e, enorm, dist, enc, idxarr, counter, list);
    hipLaunchKernelGGL(k3_refine, dim3(512),  dim3(256), 0, stream, x, e, list, counter, idxarr);
    hipLaunchKernelGGL(k5_final,  dim3(8192), dim3(256), 0, stream, x, eT, idxarr, outq, enc, outidx, cnt, partials);
    hipLaunchKernelGGL(k6_scalar, dim3(1),    dim3(256), 0, stream, partials, cnt, outloss, outperp);
}

// Round 2
// 502.514 us; speedup vs baseline: 1.4777x; 1.4777x over previous
//
#include <hip/hip_runtime.h>
#include <hip/hip_bf16.h>
#include <math.h>

// Problem constants
#define NROWS 131072      // 32*64*64
#define DDIM  64
#define KCODE 1024
#define TAU_B 0.02f       // bf16-split dot err <= ~6e-4; 30x safety margin

// d_out layout (float elements, return order)
#define OFF_Q    0L
#define OFF_LOSS 8388608L
#define OFF_PERP 8388609L
#define OFF_ENC  8388610L
#define OFF_IDX  (OFF_ENC + 134217728L)   // 142606338
#define OFF_DIST (OFF_IDX + 131072L)      // 142737410

// ws layout (float elements)
#define WS_ENORM 0L          // 1024 f
#define WS_ET    1024L       // 65536 f   eT[k][d]
#define WS_EBPH  66560L      // 32768 f = 65536 ushort (packed B hi)  [16B aligned]
#define WS_EBPL  99328L      // 32768 f
#define WS_IDX   132096L     // 131072 int
#define WS_CNT   263168L     // 1024 int
#define WS_CTR   264192L     // 4 int
#define WS_LIST  264196L     // 131072 int
#define WS_PART  395268L     // 2048 f

typedef short bf16x8 __attribute__((ext_vector_type(8)));
typedef float f32x4  __attribute__((ext_vector_type(4)));

__device__ inline unsigned short f2bf(float f) {
    unsigned u = __float_as_uint(f);
    unsigned r = (u + 0x7fffu + ((u >> 16) & 1u)) >> 16;
    return (unsigned short)r;
}
__device__ inline float bf2f(unsigned short h) {
    return __uint_as_float(((unsigned)h) << 16);
}

// ---------------- k1a: e-norms (f32), eT for gather, zero cnt/counter ----------------
__global__ __launch_bounds__(256) void k1a_prep(const float* __restrict__ e,
                                                float* __restrict__ enorm,
                                                float* __restrict__ eT,
                                                int* __restrict__ cnt,
                                                int* __restrict__ counter) {
    int k = blockIdx.x * 256 + threadIdx.x;   // grid=4 -> k in [0,1024)
    float s = 0.f;
    #pragma unroll 8
    for (int d = 0; d < DDIM; ++d) {
        float v = e[(size_t)d * KCODE + k];
        s = fmaf(v, v, s);
        eT[(size_t)k * DDIM + d] = v;
    }
    enorm[k] = s;
    cnt[k] = 0;
    if (k == 0) counter[0] = 0;
}

// ---------------- k1b: pack e into MFMA-B fragment layout, hi/lo bf16 ----------------
// B frag for 16x16x32: lane l holds B[k=(l>>4)*8+j][col=l&15], j=0..7 contiguous.
// ebp[((gct*2+ks)*64 + l)*8 + j], gct=col-tile (64), ks=K-step (2).
__global__ __launch_bounds__(128) void k1b_pack(const float* __restrict__ e,
                                                unsigned short* __restrict__ ebph,
                                                unsigned short* __restrict__ ebpl) {
    const int gct = blockIdx.x;          // 0..63
    const int ks  = threadIdx.x >> 6;    // 0..1
    const int l   = threadIdx.x & 63;
    const int col = (gct << 4) | (l & 15);
    const int kb  = (ks << 5) + ((l >> 4) << 3);
    const size_t ob = ((size_t)((gct << 1) | ks) * 64 + l) * 8;
    #pragma unroll
    for (int j = 0; j < 8; ++j) {
        float f = e[(size_t)(kb + j) * KCODE + col];
        unsigned short h = f2bf(f);
        float lo = f - bf2f(h);
        ebph[ob + j] = h;
        ebpl[ob + j] = f2bf(lo);
    }
}

// ---------------- k2: MFMA distances + enc zeros + argmin + near-tie list ----------------
// 256 thr = 4 waves, 16 rows/block. Wave w covers cols [w*256, w*256+256).
__global__ __launch_bounds__(256) void k2_dist(const float* __restrict__ x,
                                               const unsigned short* __restrict__ ebph,
                                               const unsigned short* __restrict__ ebpl,
                                               const float* __restrict__ enorm,
                                               float* __restrict__ dist,
                                               float* __restrict__ enc,
                                               int* __restrict__ idxarr,
                                               int* __restrict__ counter,
                                               int* __restrict__ list) {
    __shared__ short xh[16 * 64];
    __shared__ short xl[16 * 64];
    __shared__ float pn[16][16];
    __shared__ float xn[16];
    __shared__ float enl[KCODE];
    __shared__ float wm1[4][16], wm2[4][16];
    __shared__ int   wi1[4][16];

    const int tid  = threadIdx.x;
    const int lane = tid & 63;
    const int w    = tid >> 6;
    const int rowbase = blockIdx.x * 16;

    // stage x tile: f32 -> (hi,lo) bf16 in LDS; partial norms
    {
        float4 v = ((const float4*)(x + (size_t)rowbase * DDIM))[tid];
        int fi = tid * 4, r = fi >> 6, c = fi & 63;
        short4 h, lo;
        float fv[4] = {v.x, v.y, v.z, v.w};
        short hv[4], lv[4];
        #pragma unroll
        for (int q = 0; q < 4; ++q) {
            unsigned short hh = f2bf(fv[q]);
            hv[q] = (short)hh;
            lv[q] = (short)f2bf(fv[q] - bf2f(hh));
        }
        h  = make_short4(hv[0], hv[1], hv[2], hv[3]);
        lo = make_short4(lv[0], lv[1], lv[2], lv[3]);
        *(short4*)&xh[r * 64 + c] = h;
        *(short4*)&xl[r * 64 + c] = lo;
        pn[r][c >> 2] = fmaf(v.x, v.x, fmaf(v.y, v.y, fmaf(v.z, v.z, v.w * v.w)));
        ((float4*)enl)[tid] = ((const float4*)enorm)[tid];
    }
    __syncthreads();
    if (tid < 16) {
        float s = 0.f;
        #pragma unroll
        for (int j = 0; j < 16; ++j) s += pn[tid][j];
        xn[tid] = s;
    }
    __syncthreads();

    // A fragments (shared by all 4 waves): lane l -> row=l&15, k=(l>>4)*8+j (+32 for ks=1)
    const int arow = lane & 15, akb = (lane >> 4) << 3;
    bf16x8 ah0 = *(const bf16x8*)&xh[arow * 64 + akb];
    bf16x8 ah1 = *(const bf16x8*)&xh[arow * 64 + 32 + akb];
    bf16x8 al0 = *(const bf16x8*)&xl[arow * 64 + akb];
    bf16x8 al1 = *(const bf16x8*)&xl[arow * 64 + 32 + akb];

    float xnv[4];
    #pragma unroll
    for (int r = 0; r < 4; ++r) xnv[r] = xn[((lane >> 4) << 2) + r];

    float m1[4], m2[4];
    int   i1[4];
    #pragma unroll
    for (int r = 0; r < 4; ++r) { m1[r] = 3.4e38f; m2[r] = 3.4e38f; i1[r] = 1 << 30; }

    #pragma unroll 4
    for (int ct = 0; ct < 16; ++ct) {
        const int gct = (w << 4) | ct;
        const size_t bo = ((size_t)(gct << 1) * 64 + lane) * 8;
        bf16x8 bh0 = *(const bf16x8*)(ebph + bo);
        bf16x8 bh1 = *(const bf16x8*)(ebph + bo + 512);
        bf16x8 bl0 = *(const bf16x8*)(ebpl + bo);
        bf16x8 bl1 = *(const bf16x8*)(ebpl + bo + 512);

        f32x4 d = {0.f, 0.f, 0.f, 0.f};
        d = __builtin_amdgcn_mfma_f32_16x16x32_bf16(ah0, bh0, d, 0, 0, 0);
        d = __builtin_amdgcn_mfma_f32_16x16x32_bf16(ah1, bh1, d, 0, 0, 0);
        d = __builtin_amdgcn_mfma_f32_16x16x32_bf16(ah0, bl0, d, 0, 0, 0);
        d = __builtin_amdgcn_mfma_f32_16x16x32_bf16(ah1, bl1, d, 0, 0, 0);
        d = __builtin_amdgcn_mfma_f32_16x16x32_bf16(al0, bh0, d, 0, 0, 0);
        d = __builtin_amdgcn_mfma_f32_16x16x32_bf16(al1, bh1, d, 0, 0, 0);

        const int col = (gct << 4) | (lane & 15);
        const float env = enl[col];
        #pragma unroll
        for (int r = 0; r < 4; ++r) {
            const int row_l = ((lane >> 4) << 2) + r;
            float dv = fmaf(-2.f, d[r], xnv[r] + env);
            dist[(size_t)(rowbase + row_l) * KCODE + col] = dv;
            if (dv < m1[r]) { m2[r] = m1[r]; m1[r] = dv; i1[r] = col; }
            else if (dv < m2[r]) m2[r] = dv;
        }
    }

    // enc zeros for this block's 16 rows (float2: base is only 8B aligned)
    {
        const float2 z2 = make_float2(0.f, 0.f);
        #pragma unroll
        for (int rr = 0; rr < 16; ++rr) {
            float2* p = (float2*)(enc + (size_t)(rowbase + rr) * KCODE + (w << 8));
            p[lane]      = z2;
            p[lane + 64] = z2;
        }
    }

    // reduce argmin across the 16 lanes sharing each row group
    #pragma unroll
    for (int m = 1; m < 16; m <<= 1) {
        #pragma unroll
        for (int r = 0; r < 4; ++r) {
            float om1 = __shfl_xor(m1[r], m);
            int   oi1 = __shfl_xor(i1[r], m);
            float om2 = __shfl_xor(m2[r], m);
            if (om1 < m1[r] || (om1 == m1[r] && oi1 < i1[r])) {
                m2[r] = fminf(m1[r], om2); m1[r] = om1; i1[r] = oi1;
            } else {
                m2[r] = fminf(m2[r], om1);
            }
        }
    }
    if ((lane & 15) == 0) {
        const int g = lane >> 4;
        #pragma unroll
        for (int r = 0; r < 4; ++r) {
            wm1[w][(g << 2) + r] = m1[r];
            wm2[w][(g << 2) + r] = m2[r];
            wi1[w][(g << 2) + r] = i1[r];
        }
    }
    __syncthreads();
    if (tid < 16) {
        float bm1 = wm1[0][tid], bm2 = wm2[0][tid];
        int   bi  = wi1[0][tid];
        #pragma unroll
        for (int wv = 1; wv < 4; ++wv) {
            float om1 = wm1[wv][tid], om2 = wm2[wv][tid];
            int   oi  = wi1[wv][tid];
            if (om1 < bm1 || (om1 == bm1 && oi < bi)) {
                bm2 = fminf(bm1, om2); bm1 = om1; bi = oi;
            } else {
                bm2 = fminf(bm2, om1);
            }
        }
        const int row = rowbase + tid;
        idxarr[row] = bi;
        if (bm2 - bm1 < TAU_B) {
            int p = atomicAdd(counter, 1);
            if (p < NROWS) list[p] = row;
        }
    }
}

// ---------------- k4: f64 refinement of near-tie rows ----------------
__global__ __launch_bounds__(256) void k4_refine(const float* __restrict__ x,
                                                 const float* __restrict__ e,
                                                 const int* __restrict__ list,
                                                 const int* __restrict__ counter,
                                                 int* __restrict__ idxarr) {
    const int cntv = min(counter[0], NROWS);
    __shared__ double bv[256];
    __shared__ int    bi[256];
    __shared__ float  xsh[DDIM];
    const int tid = threadIdx.x;
    for (int li = blockIdx.x; li < cntv; li += gridDim.x) {
        const int n = list[li];
        if (tid < DDIM) xsh[tid] = x[(size_t)n * DDIM + tid];
        __syncthreads();
        const int k0 = tid * 4;
        double dd[4] = {0.0, 0.0, 0.0, 0.0};
        for (int d = 0; d < DDIM; ++d) {
            double xd = (double)xsh[d];
            float4 ev = *(const float4*)(e + (size_t)d * KCODE + k0);
            double t0 = xd - (double)ev.x; dd[0] = fma(t0, t0, dd[0]);
            double t1 = xd - (double)ev.y; dd[1] = fma(t1, t1, dd[1]);
            double t2 = xd - (double)ev.z; dd[2] = fma(t2, t2, dd[2]);
            double t3 = xd - (double)ev.w; dd[3] = fma(t3, t3, dd[3]);
        }
        double best = dd[0]; int bidx = k0;
        #pragma unroll
        for (int c = 1; c < 4; ++c)
            if (dd[c] < best) { best = dd[c]; bidx = k0 + c; }
        bv[tid] = best; bi[tid] = bidx;
        __syncthreads();
        for (int s = 128; s > 0; s >>= 1) {
            if (tid < s) {
                if (bv[tid + s] < bv[tid] ||
                    (bv[tid + s] == bv[tid] && bi[tid + s] < bi[tid])) {
                    bv[tid] = bv[tid + s]; bi[tid] = bi[tid + s];
                }
            }
            __syncthreads();
        }
        if (tid == 0) idxarr[n] = bi[0];
        __syncthreads();
    }
}

// ---------------- k5: gather quantized (float4 lanes), one-hot, indices, SSE, histogram ----------------
// 2048 blocks x 256 thr, 64 rows/block. Lane covers 16B of a row.
__global__ __launch_bounds__(256) void k5_final(const float* __restrict__ x,
                                                const float* __restrict__ eT,
                                                const int* __restrict__ idxarr,
                                                float* __restrict__ outq,
                                                float* __restrict__ enc,
                                                float* __restrict__ outidx,
                                                int* __restrict__ cnt,
                                                float* __restrict__ partials) {
    const int tid = threadIdx.x;
    const int rowbase = blockIdx.x * 64;
    const int col4 = tid & 15;
    float sse = 0.f;
    #pragma unroll
    for (int it = 0; it < 4; ++it) {
        const int row = (it << 4) + (tid >> 4);
        const int grow = rowbase + row;
        const int idx = idxarr[grow];
        float4 ev = ((const float4*)eT)[idx * 16 + col4];
        float4 xv = ((const float4*)x)[grow * 16 + col4];
        ((float4*)outq)[grow * 16 + col4] = ev;
        float d0 = ev.x - xv.x, d1 = ev.y - xv.y, d2 = ev.z - xv.z, d3 = ev.w - xv.w;
        sse = fmaf(d0, d0, fmaf(d1, d1, fmaf(d2, d2, fmaf(d3, d3, sse))));
    }
    if (tid < 64) {
        const int grow = rowbase + tid;
        const int idx = idxarr[grow];
        outidx[grow] = (float)idx;
        enc[(size_t)grow * KCODE + idx] = 1.0f;
        atomicAdd(cnt + idx, 1);
    }
    // block SSE reduce
    #pragma unroll
    for (int m = 1; m < 64; m <<= 1) sse += __shfl_xor(sse, m);
    __shared__ float ps[4];
    if ((tid & 63) == 0) ps[tid >> 6] = sse;
    __syncthreads();
    if (tid == 0) partials[blockIdx.x] = ps[0] + ps[1] + ps[2] + ps[3];
}

// ---------------- k6: loss + perplexity ----------------
__global__ __launch_bounds__(256) void k6_scalar(const float* __restrict__ partials,
                                                 const int* __restrict__ cnt,
                                                 float* __restrict__ outloss,
                                                 float* __restrict__ outperp) {
    __shared__ double sd[256];
    const int tid = threadIdx.x;
    double s = 0.0;
    for (int i = tid; i < 2048; i += 256) s += (double)partials[i];
    sd[tid] = s;
    __syncthreads();
    for (int st = 128; st > 0; st >>= 1) {
        if (tid < st) sd[tid] += sd[tid + st];
        __syncthreads();
    }
    const double total = sd[0];
    __syncthreads();
    double h = 0.0;
    for (int k = tid; k < KCODE; k += 256) {
        double p = (double)cnt[k] / (double)NROWS;
        h -= p * log(p + 1e-10);
    }
    sd[tid] = h;
    __syncthreads();
    for (int st = 128; st > 0; st >>= 1) {
        if (tid < st) sd[tid] += sd[tid + st];
        __syncthreads();
    }
    if (tid == 0) {
        *outloss = (float)(total * 1.25 / (double)((long)NROWS * DDIM));
        *outperp = (float)exp(sd[0]);
    }
}

extern "C" void kernel_launch(void* const* d_in, const int* in_sizes, int n_in,
                              void* d_out, int out_size, void* d_ws, size_t ws_size,
                              hipStream_t stream) {
    const float* x = (const float*)d_in[0];       // [131072, 64]
    const float* e = (const float*)d_in[1];       // [64, 1024]
    float* out = (float*)d_out;

    float* ws_f = (float*)d_ws;
    float* enorm   = ws_f + WS_ENORM;
    float* eT      = ws_f + WS_ET;
    unsigned short* ebph = (unsigned short*)(ws_f + WS_EBPH);
    unsigned short* ebpl = (unsigned short*)(ws_f + WS_EBPL);
    int*   idxarr  = (int*)(ws_f + WS_IDX);
    int*   cnt     = (int*)(ws_f + WS_CNT);
    int*   counter = (int*)(ws_f + WS_CTR);
    int*   list    = (int*)(ws_f + WS_LIST);
    float* partials= ws_f + WS_PART;

    float* outq    = out + OFF_Q;
    float* outloss = out + OFF_LOSS;
    float* outperp = out + OFF_PERP;
    float* enc     = out + OFF_ENC;
    float* outidx  = out + OFF_IDX;
    float* dist    = out + OFF_DIST;

    hipLaunchKernelGGL(k1a_prep, dim3(4),    dim3(256), 0, stream, e, enorm, eT, cnt, counter);
    hipLaunchKernelGGL(k1b_pack, dim3(64),   dim3(128), 0, stream, e, ebph, ebpl);
    hipLaunchKernelGGL(k2_dist,  dim3(8192), dim3(256), 0, stream, x, ebph, ebpl, enorm,
                       dist, enc, idxarr, counter, list);
    hipLaunchKernelGGL(k4_refine,dim3(256),  dim3(256), 0, stream, x, e, list, counter, idxarr);
    hipLaunchKernelGGL(k5_final, dim3(2048), dim3(256), 0, stream, x, eT, idxarr, outq, enc, outidx, cnt, partials);
    hipLaunchKernelGGL(k6_scalar,dim3(1),    dim3(256), 0, stream, partials, cnt, outloss, outperp);
}

// Round 3
// 457.037 us; speedup vs baseline: 1.6247x; 1.0995x over previous
//
#include <hip/hip_runtime.h>
#include <hip/hip_bf16.h>
#include <math.h>

// Problem constants
#define NROWS 131072      // 32*64*64
#define DDIM  64
#define KCODE 1024
#define TAU_B 0.008f      // split-bf16 dist err <= ~2e-3; 4x margin

// d_out layout (float elements, return order)
#define OFF_Q    0L
#define OFF_LOSS 8388608L
#define OFF_PERP 8388609L
#define OFF_ENC  8388610L                 // NOTE: only 8B-aligned
#define OFF_IDX  (OFF_ENC + 134217728L)   // 142606338
#define OFF_DIST (OFF_IDX + 131072L)      // 142737410 — only 8B-aligned

// ws layout (float elements)
#define WS_ENORM 0L          // 1024 f
#define WS_ET    1024L       // 65536 f   eT[k][d]
#define WS_EBPH  66560L      // 32768 f = 65536 ushort (packed B hi)
#define WS_EBPL  99328L      // 32768 f
#define WS_IDX   132096L     // 131072 int
#define WS_CNT   263168L     // 1024 int
#define WS_CTR   264192L     // 4 int
#define WS_LIST  264196L     // 131072 int
#define WS_PART  395268L     // 8192 f

typedef short bf16x8 __attribute__((ext_vector_type(8)));
typedef float f32x4  __attribute__((ext_vector_type(4)));

__device__ inline unsigned short f2bf(float f) {
    unsigned u = __float_as_uint(f);
    unsigned r = (u + 0x7fffu + ((u >> 16) & 1u)) >> 16;
    return (unsigned short)r;
}
__device__ inline float bf2f(unsigned short h) {
    return __uint_as_float(((unsigned)h) << 16);
}

// ---------------- k1a: e-norms (f32), eT for gather, zero cnt/counter ----------------
__global__ __launch_bounds__(256) void k1a_prep(const float* __restrict__ e,
                                                float* __restrict__ enorm,
                                                float* __restrict__ eT,
                                                int* __restrict__ cnt,
                                                int* __restrict__ counter) {
    int k = blockIdx.x * 256 + threadIdx.x;   // grid=4 -> k in [0,1024)
    float s = 0.f;
    #pragma unroll 8
    for (int d = 0; d < DDIM; ++d) {
        float v = e[(size_t)d * KCODE + k];
        s = fmaf(v, v, s);
        eT[(size_t)k * DDIM + d] = v;
    }
    enorm[k] = s;
    cnt[k] = 0;
    if (k == 0) counter[0] = 0;
}

// ---------------- k1b: pack e into MFMA-B fragment layout, hi/lo bf16 ----------------
__global__ __launch_bounds__(128) void k1b_pack(const float* __restrict__ e,
                                                unsigned short* __restrict__ ebph,
                                                unsigned short* __restrict__ ebpl) {
    const int gct = blockIdx.x;          // 0..63
    const int ks  = threadIdx.x >> 6;    // 0..1
    const int l   = threadIdx.x & 63;
    const int col = (gct << 4) | (l & 15);
    const int kb  = (ks << 5) + ((l >> 4) << 3);
    const size_t ob = ((size_t)((gct << 1) | ks) * 64 + l) * 8;
    #pragma unroll
    for (int j = 0; j < 8; ++j) {
        float f = e[(size_t)(kb + j) * KCODE + col];
        unsigned short h = f2bf(f);
        float lo = f - bf2f(h);
        ebph[ob + j] = h;
        ebpl[ob + j] = f2bf(lo);
    }
}

// ---------------- kB: MFMA distances + argmin + near-tie list + loss partials ----------------
// 256 thr = 4 waves, 16 rows/block. Wave w covers cols [w*256, (w+1)*256).
// Accumulator is transposed through per-wave LDS so each lane owns 4 consecutive
// cols of one row -> contiguous float2 stores with a single base pointer.
__global__ __launch_bounds__(256) void kB_dist(const float* __restrict__ x,
                                               const unsigned short* __restrict__ ebph,
                                               const unsigned short* __restrict__ ebpl,
                                               const float* __restrict__ enorm,
                                               float* __restrict__ dist,
                                               int* __restrict__ idxarr,
                                               int* __restrict__ counter,
                                               int* __restrict__ list,
                                               float* __restrict__ partials) {
    __shared__ short xh[16 * 64];
    __shared__ short xl[16 * 64];
    __shared__ float pn[16][16];
    __shared__ float xn[16];
    __shared__ float enl[KCODE];
    __shared__ float tr[4][16 * 24];      // per-wave 16x16 transpose tile, pad 24
    __shared__ float wm1[4][16], wm2[4][16];
    __shared__ int   wi1[4][16];
    __shared__ float ps[16];

    const int tid  = threadIdx.x;
    const int lane = tid & 63;
    const int w    = tid >> 6;
    const int rowbase = blockIdx.x * 16;

    // stage x tile: f32 -> (hi,lo) bf16 in LDS; partial norms; enorm -> LDS
    {
        float4 v = ((const float4*)(x + (size_t)rowbase * DDIM))[tid];
        int fi = tid * 4, r = fi >> 6, c = fi & 63;
        float fv[4] = {v.x, v.y, v.z, v.w};
        short hv[4], lv[4];
        #pragma unroll
        for (int q = 0; q < 4; ++q) {
            unsigned short hh = f2bf(fv[q]);
            hv[q] = (short)hh;
            lv[q] = (short)f2bf(fv[q] - bf2f(hh));
        }
        *(short4*)&xh[r * 64 + c] = make_short4(hv[0], hv[1], hv[2], hv[3]);
        *(short4*)&xl[r * 64 + c] = make_short4(lv[0], lv[1], lv[2], lv[3]);
        pn[r][c >> 2] = fmaf(v.x, v.x, fmaf(v.y, v.y, fmaf(v.z, v.z, v.w * v.w)));
        ((float4*)enl)[tid] = ((const float4*)enorm)[tid];
    }
    __syncthreads();
    if (tid < 16) {
        float s = 0.f;
        #pragma unroll
        for (int j = 0; j < 16; ++j) s += pn[tid][j];
        xn[tid] = s;
    }
    __syncthreads();

    // A fragments: lane l -> row=l&15, k=(l>>4)*8+j (+32 for second K-step)
    const int arow = lane & 15, akb = (lane >> 4) << 3;
    bf16x8 ah0 = *(const bf16x8*)&xh[arow * 64 + akb];
    bf16x8 ah1 = *(const bf16x8*)&xh[arow * 64 + 32 + akb];
    bf16x8 al0 = *(const bf16x8*)&xl[arow * 64 + akb];
    bf16x8 al1 = *(const bf16x8*)&xl[arow * 64 + 32 + akb];

    const int myrow = lane >> 2;            // 0..15 after transpose
    const int cgrp  = lane & 3;             // 4-col group
    const float xnv = xn[myrow];
    float* tp = &tr[w][0];
    const int wr = (lane >> 4) << 2;        // accumulator row block for writes
    const int wx = myrow * 24 + (cgrp << 2);
    float* dp = dist + (size_t)(rowbase + myrow) * KCODE + (w << 8) + (cgrp << 2);
    const int colbase = (w << 8) + (cgrp << 2);

    float m1 = 3.4e38f, m2 = 3.4e38f;
    int   i1 = 1 << 30;

    #pragma unroll 4
    for (int ct = 0; ct < 16; ++ct) {
        const int gct = (w << 4) | ct;
        const size_t bo = ((size_t)(gct << 1) * 64 + lane) * 8;
        bf16x8 bh0 = *(const bf16x8*)(ebph + bo);
        bf16x8 bh1 = *(const bf16x8*)(ebph + bo + 512);
        bf16x8 bl0 = *(const bf16x8*)(ebpl + bo);
        bf16x8 bl1 = *(const bf16x8*)(ebpl + bo + 512);

        f32x4 d = {0.f, 0.f, 0.f, 0.f};
        d = __builtin_amdgcn_mfma_f32_16x16x32_bf16(ah0, bh0, d, 0, 0, 0);
        d = __builtin_amdgcn_mfma_f32_16x16x32_bf16(ah1, bh1, d, 0, 0, 0);
        d = __builtin_amdgcn_mfma_f32_16x16x32_bf16(ah0, bl0, d, 0, 0, 0);
        d = __builtin_amdgcn_mfma_f32_16x16x32_bf16(ah1, bl1, d, 0, 0, 0);
        d = __builtin_amdgcn_mfma_f32_16x16x32_bf16(al0, bh0, d, 0, 0, 0);
        d = __builtin_amdgcn_mfma_f32_16x16x32_bf16(al1, bh1, d, 0, 0, 0);

        // wave-local transpose: write C-fragment layout, read row-major float4
        tp[(wr + 0) * 24 + (lane & 15)] = d[0];
        tp[(wr + 1) * 24 + (lane & 15)] = d[1];
        tp[(wr + 2) * 24 + (lane & 15)] = d[2];
        tp[(wr + 3) * 24 + (lane & 15)] = d[3];
        float4 dv = *(float4*)&tp[wx];
        float4 en4 = *(float4*)&enl[(w << 8) + (ct << 4) + (cgrp << 2)];

        float o0 = fmaf(-2.f, dv.x, xnv + en4.x);
        float o1 = fmaf(-2.f, dv.y, xnv + en4.y);
        float o2 = fmaf(-2.f, dv.z, xnv + en4.z);
        float o3 = fmaf(-2.f, dv.w, xnv + en4.w);

        const int c0 = colbase + (ct << 4);
        if (o0 < m1) { m2 = m1; m1 = o0; i1 = c0; }     else if (o0 < m2) m2 = o0;
        if (o1 < m1) { m2 = m1; m1 = o1; i1 = c0 + 1; } else if (o1 < m2) m2 = o1;
        if (o2 < m1) { m2 = m1; m1 = o2; i1 = c0 + 2; } else if (o2 < m2) m2 = o2;
        if (o3 < m1) { m2 = m1; m1 = o3; i1 = c0 + 3; } else if (o3 < m2) m2 = o3;

        *(float2*)(dp + (ct << 4))     = make_float2(o0, o1);
        *(float2*)(dp + (ct << 4) + 2) = make_float2(o2, o3);
    }

    // merge across the 4 col-group lanes of each row (xor 1, 2), tie -> lower index
    #pragma unroll
    for (int m = 1; m < 4; m <<= 1) {
        float om1 = __shfl_xor(m1, m);
        int   oi1 = __shfl_xor(i1, m);
        float om2 = __shfl_xor(m2, m);
        if (om1 < m1 || (om1 == m1 && oi1 < i1)) {
            m2 = fminf(m1, om2); m1 = om1; i1 = oi1;
        } else {
            m2 = fminf(m2, om1);
        }
    }
    if (cgrp == 0) { wm1[w][myrow] = m1; wm2[w][myrow] = m2; wi1[w][myrow] = i1; }
    __syncthreads();
    if (tid < 16) {
        float bm1 = wm1[0][tid], bm2 = wm2[0][tid];
        int   bi  = wi1[0][tid];
        #pragma unroll
        for (int wv = 1; wv < 4; ++wv) {
            float om1 = wm1[wv][tid], om2 = wm2[wv][tid];
            int   oi  = wi1[wv][tid];
            if (om1 < bm1 || (om1 == bm1 && oi < bi)) {
                bm2 = fminf(bm1, om2); bm1 = om1; bi = oi;
            } else {
                bm2 = fminf(bm2, om1);
            }
        }
        const int row = rowbase + tid;
        idxarr[row] = bi;
        ps[tid] = bm1;                      // min-dist == ||x-q||^2 for loss
        if (bm2 - bm1 < TAU_B) {
            int p = atomicAdd(counter, 1);
            if (p < NROWS) list[p] = row;
        }
    }
    __syncthreads();
    if (tid == 0) {
        float s = 0.f;
        #pragma unroll
        for (int j = 0; j < 16; ++j) s += ps[j];
        partials[blockIdx.x] = s;
    }
}

// ---------------- k4: f64 refinement of near-tie rows ----------------
__global__ __launch_bounds__(256) void k4_refine(const float* __restrict__ x,
                                                 const float* __restrict__ e,
                                                 const int* __restrict__ list,
                                                 const int* __restrict__ counter,
                                                 int* __restrict__ idxarr) {
    const int cntv = min(counter[0], NROWS);
    __shared__ double bv[256];
    __shared__ int    bi[256];
    __shared__ float  xsh[DDIM];
    const int tid = threadIdx.x;
    for (int li = blockIdx.x; li < cntv; li += gridDim.x) {
        const int n = list[li];
        if (tid < DDIM) xsh[tid] = x[(size_t)n * DDIM + tid];
        __syncthreads();
        const int k0 = tid * 4;
        double dd[4] = {0.0, 0.0, 0.0, 0.0};
        for (int d = 0; d < DDIM; ++d) {
            double xd = (double)xsh[d];
            float4 ev = *(const float4*)(e + (size_t)d * KCODE + k0);
            double t0 = xd - (double)ev.x; dd[0] = fma(t0, t0, dd[0]);
            double t1 = xd - (double)ev.y; dd[1] = fma(t1, t1, dd[1]);
            double t2 = xd - (double)ev.z; dd[2] = fma(t2, t2, dd[2]);
            double t3 = xd - (double)ev.w; dd[3] = fma(t3, t3, dd[3]);
        }
        double best = dd[0]; int bidx = k0;
        #pragma unroll
        for (int c = 1; c < 4; ++c)
            if (dd[c] < best) { best = dd[c]; bidx = k0 + c; }
        bv[tid] = best; bi[tid] = bidx;
        __syncthreads();
        for (int s = 128; s > 0; s >>= 1) {
            if (tid < s) {
                if (bv[tid + s] < bv[tid] ||
                    (bv[tid + s] == bv[tid] && bi[tid + s] < bi[tid])) {
                    bv[tid] = bv[tid + s]; bi[tid] = bi[tid + s];
                }
            }
            __syncthreads();
        }
        if (tid == 0) idxarr[n] = bi[0];
        __syncthreads();
    }
}

// ---------------- kC: fused enc(one-hot folded) + outq gather + indices + hist ----------------
// 2048 blocks x 256 thr, 64 rows/block.
__global__ __launch_bounds__(256) void kC_final(const float* __restrict__ eT,
                                                const int* __restrict__ idxarr,
                                                float* __restrict__ outq,
                                                float* __restrict__ enc,    // 8B-aligned
                                                float* __restrict__ outidx,
                                                int* __restrict__ cnt) {
    __shared__ int sidx[64];
    const int tid = threadIdx.x;
    const int rowbase = blockIdx.x * 64;

    if (tid < 64) {
        const int grow = rowbase + tid;
        const int idx = idxarr[grow];
        sidx[tid] = idx;
        outidx[grow] = (float)idx;
        atomicAdd(cnt + idx, 1);
    }
    __syncthreads();

    // outq: gather codebook rows, float4 lanes (16 lanes/row)
    #pragma unroll
    for (int it = 0; it < 4; ++it) {
        const int row = (it << 4) + (tid >> 4);
        const int grow = rowbase + row;
        const int idx = sidx[row];
        float4 ev = ((const float4*)eT)[idx * 16 + (tid & 15)];
        ((float4*)outq)[(size_t)grow * 16 + (tid & 15)] = ev;
    }

    // enc: stream zeros with the one-hot folded in. float2 (base 8B-aligned).
    float2* e2 = (float2*)enc;
    for (int r = 0; r < 64; ++r) {
        const int idx = sidx[r];
        const size_t rb = ((size_t)(rowbase + r) << 9);
        #pragma unroll
        for (int h = 0; h < 2; ++h) {
            const int col = (h << 9) + (tid << 1);
            float2 v;
            v.x = (col     == idx) ? 1.f : 0.f;
            v.y = (col + 1 == idx) ? 1.f : 0.f;
            e2[rb + (h << 8) + tid] = v;
        }
    }
}

// ---------------- k6: loss + perplexity ----------------
__global__ __launch_bounds__(256) void k6_scalar(const float* __restrict__ partials,
                                                 const int* __restrict__ cnt,
                                                 float* __restrict__ outloss,
                                                 float* __restrict__ outperp) {
    __shared__ double sd[256];
    const int tid = threadIdx.x;
    double s = 0.0;
    for (int i = tid; i < 8192; i += 256) s += (double)partials[i];
    sd[tid] = s;
    __syncthreads();
    for (int st = 128; st > 0; st >>= 1) {
        if (tid < st) sd[tid] += sd[tid + st];
        __syncthreads();
    }
    const double total = sd[0];
    __syncthreads();
    double h = 0.0;
    for (int k = tid; k < KCODE; k += 256) {
        double p = (double)cnt[k] / (double)NROWS;
        h -= p * log(p + 1e-10);
    }
    sd[tid] = h;
    __syncthreads();
    for (int st = 128; st > 0; st >>= 1) {
        if (tid < st) sd[tid] += sd[tid + st];
        __syncthreads();
    }
    if (tid == 0) {
        *outloss = (float)(total * 1.25 / (double)((long)NROWS * DDIM));
        *outperp = (float)exp(sd[0]);
    }
}

extern "C" void kernel_launch(void* const* d_in, const int* in_sizes, int n_in,
                              void* d_out, int out_size, void* d_ws, size_t ws_size,
                              hipStream_t stream) {
    const float* x = (const float*)d_in[0];       // [131072, 64]
    const float* e = (const float*)d_in[1];       // [64, 1024]
    float* out = (float*)d_out;

    float* ws_f = (float*)d_ws;
    float* enorm   = ws_f + WS_ENORM;
    float* eT      = ws_f + WS_ET;
    unsigned short* ebph = (unsigned short*)(ws_f + WS_EBPH);
    unsigned short* ebpl = (unsigned short*)(ws_f + WS_EBPL);
    int*   idxarr  = (int*)(ws_f + WS_IDX);
    int*   cnt     = (int*)(ws_f + WS_CNT);
    int*   counter = (int*)(ws_f + WS_CTR);
    int*   list    = (int*)(ws_f + WS_LIST);
    float* partials= ws_f + WS_PART;

    float* outq    = out + OFF_Q;
    float* outloss = out + OFF_LOSS;
    float* outperp = out + OFF_PERP;
    float* enc     = out + OFF_ENC;
    float* outidx  = out + OFF_IDX;
    float* dist    = out + OFF_DIST;

    hipLaunchKernelGGL(k1a_prep, dim3(4),    dim3(256), 0, stream, e, enorm, eT, cnt, counter);
    hipLaunchKernelGGL(k1b_pack, dim3(64),   dim3(128), 0, stream, e, ebph, ebpl);
    hipLaunchKernelGGL(kB_dist,  dim3(8192), dim3(256), 0, stream, x, ebph, ebpl, enorm,
                       dist, idxarr, counter, list, partials);
    hipLaunchKernelGGL(k4_refine,dim3(128),  dim3(256), 0, stream, x, e, list, counter, idxarr);
    hipLaunchKernelGGL(kC_final, dim3(2048), dim3(256), 0, stream, eT, idxarr, outq, enc, outidx, cnt);
    hipLaunchKernelGGL(k6_scalar,dim3(1),    dim3(256), 0, stream, partials, cnt, outloss, outperp);
}